// Round 9
// baseline (144.730 us; speedup 1.0000x reference)
//
#include <hip/hip_runtime.h>

#define BB 4
#define CC 32
#define HH 512
#define WW 500
#define SS 10
#define SW 50
#define P2 (WW / 2)       // 250 float2 columns per row
#define NREP 8            // one accumulator replica per XCD
#define REP_STRIDE 1344   // 1280 chan + 40 tex, padded to 21*64B lines

// ---------------- Stage 1: strip channel sums + texture energy ----------------
// One block per (b, row): grid = 4*512 = 2048 blocks -> 8 blocks/CU -> 32 waves/CU.
// Thread owns one float2 column (both pixels in ONE strip since 2|50).
// LDS-atomic reduction per (strip,channel), then global atomics into the
// per-XCD replica (blk & 7) -> atomics stay in one XCD's L2, no cross-XCD
// line ping-pong (R8's 70 MB WRITE_SIZE collapse).
__global__ __launch_bounds__(256, 8)
void pan_stage1(const float* __restrict__ x,
                float* __restrict__ rep)    // [NREP][REP_STRIDE]
{
    const int tid = threadIdx.x;
    const int blk = blockIdx.x;
    const int b   = blk / HH;
    const int h   = blk % HH;
    const int p   = tid;                 // float2 column index
    const bool active = (p < P2);
    const int s   = p / (SW / 2);        // strip (25 float2 per strip)

    __shared__ float lds_c[SS * CC];     // 320 > blockDim: stride loops
    __shared__ float lds_t[SS];
    for (int i = tid; i < SS * CC; i += 256) lds_c[i] = 0.0f;
    if (tid < SS) lds_t[tid] = 0.0f;
    __syncthreads();

    if (active) {
        const float* base = x + (size_t)b * CC * HH * WW + (size_t)h * WW + 2 * p;
        float csum[CC];
        float gx = 0.0f, gy = 0.0f;
#pragma unroll
        for (int c = 0; c < CC; ++c) {
            const float2 v = *reinterpret_cast<const float2*>(base + (size_t)c * HH * WW);
            csum[c] = v.x + v.y;
            gx += v.x;
            gy += v.y;
        }
#pragma unroll
        for (int c = 0; c < CC; ++c) atomicAdd(&lds_c[s * CC + c], csum[c]);
        atomicAdd(&lds_t[s], gx * gx + gy * gy);
    }
    __syncthreads();

    float* r = rep + (size_t)(blk & (NREP - 1)) * REP_STRIDE;
    for (int i = tid; i < SS * CC; i += 256) atomicAdd(r + b * SS * CC + i, lds_c[i]);
    if (tid < SS) atomicAdd(r + BB * SS * CC + b * SS + tid, lds_t[tid]);
}

// ---------------- Stage 2: replica sum, feats, hierarchy+reg, loss, tree ----------------
// 1024 threads; 1280-element phases use stride loops.
__global__ __launch_bounds__(1024)
void pan_stage2(const float* __restrict__ rep,
                float* __restrict__ out)
{
    __shared__ float feats[BB][SS][CC];   // 1280
    __shared__ float cur1[BB][5][CC];     // 640
    __shared__ float cur2[BB][3][CC];     // 384
    __shared__ float cur3[BB][2][CC];     // 256
    __shared__ float cur4[BB][1][CC];     // 128
    __shared__ float red[1024];
    const int t = threadIdx.x;

    // feats = 0.5 * nodes + 0.5 * texture   (1280 elements, strided; 8-replica sum inline)
    for (int i = t; i < BB * SS * CC; i += 1024) {
        int b = i / (SS * CC);
        int s = (i / CC) % SS;
        float chansum = 0.0f, texsum = 0.0f;
#pragma unroll
        for (int r = 0; r < NREP; ++r) {
            chansum += rep[r * REP_STRIDE + i];
            texsum  += rep[r * REP_STRIDE + BB * SS * CC + b * SS + s];
        }
        float node    = chansum * (1.0f / (HH * SW));        // /25600
        float texture = texsum * (1.0f / (CC * CC));         // tsum/1024
        ((float*)feats)[i] = 0.5f * node + 0.5f * texture;
    }
    __syncthreads();

    if (t < BB * 5 * CC) {   // 640
        int b = t / (5 * CC), j = (t / CC) % 5, c = t % CC;
        cur1[b][j][c] = 0.5f * (feats[b][2 * j][c] + feats[b][2 * j + 1][c]);
    }
    __syncthreads();
    if (t < BB * 3 * CC) {   // 384
        int b = t / (3 * CC), j = (t / CC) % 3, c = t % CC;
        cur2[b][j][c] = (j < 2) ? 0.5f * (cur1[b][2 * j][c] + cur1[b][2 * j + 1][c])
                                : cur1[b][4][c];
    }
    __syncthreads();
    if (t < BB * 2 * CC) {   // 256
        int b = t / (2 * CC), j = (t / CC) % 2, c = t % CC;
        cur3[b][j][c] = (j == 0) ? 0.5f * (cur2[b][0][c] + cur2[b][1][c])
                                 : cur2[b][2][c];
    }
    __syncthreads();
    if (t < BB * CC) {       // 128
        int b = t / CC, c = t % CC;
        cur4[b][0][c] = 0.5f * (cur3[b][0][c] + cur3[b][1][c]);
    }
    __syncthreads();

    // reg = sum of per-level means of cur^2
    float rp = 0.0f;
    for (int i = t; i < BB * 5 * CC; i += 1024) { float v = ((float*)cur1)[i]; rp += v * v * (1.0f / (BB * 5 * CC)); }
    for (int i = t; i < BB * 3 * CC; i += 1024) { float v = ((float*)cur2)[i]; rp += v * v * (1.0f / (BB * 3 * CC)); }
    for (int i = t; i < BB * 2 * CC; i += 1024) { float v = ((float*)cur3)[i]; rp += v * v * (1.0f / (BB * 2 * CC)); }
    for (int i = t; i < BB * 1 * CC; i += 1024) { float v = ((float*)cur4)[i]; rp += v * v * (1.0f / (BB * 1 * CC)); }

    // pairwise contrastive term over leaves (400 pairs)
    float lp = 0.0f;
    if (t < BB * SS * SS) {
        int b = t / (SS * SS), i = (t / SS) % SS, j = t % SS;
        float d2 = 0.0f;
#pragma unroll
        for (int c = 0; c < CC; ++c) {
            float df = feats[b][i][c] - feats[b][j][c];
            d2 += df * df;
        }
        float d = sqrtf(d2 + 1e-12f);
        int lev;
        if (i == j) lev = 0;
        else if ((i >> 1) == (j >> 1)) lev = 1;
        else {
            int g2i = (i < 4) ? 0 : ((i < 8) ? 1 : 2);
            int g2j = (j < 4) ? 0 : ((j < 8) ? 1 : 2);
            if (g2i == g2j) lev = 2;
            else if ((i < 8) == (j < 8)) lev = 3;
            else lev = 4;
        }
        float w = 1.0f - 0.25f * (float)lev;
        float m = fmaxf(1.0f - d, 0.0f);
        lp = w * d * d + (1.0f - w) * m * m;
    }

    // reduce pairwise sum
    red[t] = lp;
    __syncthreads();
    for (int off = 512; off >= 1; off >>= 1) {
        if (t < off) red[t] += red[t + off];
        __syncthreads();
    }
    float lsum = red[0];
    __syncthreads();
    // reduce reg partials
    red[t] = rp;
    __syncthreads();
    for (int off = 512; off >= 1; off >>= 1) {
        if (t < off) red[t] += red[t + off];
        __syncthreads();
    }
    if (t == 0) out[BB * 21 * 2] = lsum * (1.0f / (BB * SS * SS)) + 0.01f * red[0];

    // tree: [B, 21, 2] = (parent, level), written as float32 (168 elements)
    if (t < BB * 21 * 2) {
        int g = (t % 42) >> 1;
        int k = t & 1;
        int par, lv;
        if (g < 10)      { par = 10 + (g >> 1);        lv = 0; }
        else if (g < 15) { par = 15 + ((g - 10) >> 1); lv = 1; }
        else if (g < 18) { par = 18 + ((g - 15) >> 1); lv = 2; }
        else if (g < 20) { par = 20;                   lv = 3; }
        else             { par = 20;                   lv = 4; }
        out[t] = (float)(k ? lv : par);
    }
}

extern "C" void kernel_launch(void* const* d_in, const int* in_sizes, int n_in,
                              void* d_out, int out_size, void* d_ws, size_t ws_size,
                              hipStream_t stream) {
    const float* x = (const float*)d_in[0];
    float* out = (float*)d_out;
    float* rep = (float*)d_ws;             // [NREP][REP_STRIDE] = 43 KB

    hipMemsetAsync(d_ws, 0, (size_t)NREP * REP_STRIDE * sizeof(float), stream);
    pan_stage1<<<BB * HH, 256, 0, stream>>>(x, rep);
    pan_stage2<<<1, 1024, 0, stream>>>(rep, out);
}

// Round 10
// 142.726 us; speedup vs baseline: 1.0140x; 1.0140x over previous
//
#include <hip/hip_runtime.h>

#define BB 4
#define CC 32
#define HH 512
#define WW 500
#define SS 10
#define SW 50
#define P2 (WW / 2)       // 250 float2 columns per row
#define PB 336            // padded partials row: 320 chan + 10 tex + 6 pad
#define NBLK (BB * HH)    // 2048 stage-1 blocks
#define RPI HH            // rows (blocks) per image

// ws layout (floats): partials[NBLK][PB] | chan[BB*SS*CC] | tex[BB*SS]
#define WS_PARTIALS 0
#define WS_CHAN (NBLK * PB)
#define WS_TEX  (WS_CHAN + BB * SS * CC)

// ---------------- Stage 1: per-row strip sums -> unique partial slot ----------------
// One block per (b, row): 2048 blocks -> 8 blocks/CU -> 32 waves/CU occupancy.
// Thread owns one float2 column (both pixels in ONE strip since 2|50).
// LDS-atomic reduction per (strip,channel) inside the block, then PLAIN coalesced
// stores to partials[blk][*]. No global atomics (R8/R9: 676k device-scope RMWs
// cost ~126us at a fixed ~104B/op coherence toll regardless of address spread).
__global__ __launch_bounds__(256, 8)
void pan_stage1(const float* __restrict__ x,
                float* __restrict__ partials)   // [NBLK][PB]
{
    const int tid = threadIdx.x;
    const int blk = blockIdx.x;
    const int b   = blk / HH;
    const int h   = blk % HH;
    const int p   = tid;                 // float2 column index
    const bool active = (p < P2);
    const int s   = p / (SW / 2);        // strip (25 float2 per strip)

    __shared__ float lds_c[SS * CC];     // 320 > blockDim: stride loops
    __shared__ float lds_t[SS];
    for (int i = tid; i < SS * CC; i += 256) lds_c[i] = 0.0f;
    if (tid < SS) lds_t[tid] = 0.0f;
    __syncthreads();

    if (active) {
        const float* base = x + (size_t)b * CC * HH * WW + (size_t)h * WW + 2 * p;
        float csum[CC];
        float gx = 0.0f, gy = 0.0f;
#pragma unroll
        for (int c = 0; c < CC; ++c) {
            const float2 v = *reinterpret_cast<const float2*>(base + (size_t)c * HH * WW);
            csum[c] = v.x + v.y;
            gx += v.x;
            gy += v.y;
        }
#pragma unroll
        for (int c = 0; c < CC; ++c) atomicAdd(&lds_c[s * CC + c], csum[c]);
        atomicAdd(&lds_t[s], gx * gx + gy * gy);
    }
    __syncthreads();

    float* dst = partials + (size_t)blk * PB;
    for (int i = tid; i < SS * CC; i += 256) dst[i] = lds_c[i];          // coalesced
    if (tid < SS) dst[SS * CC + tid] = lds_t[tid];
}

// ---------------- Stage 1b: column-reduce partials -> chan/tex ----------------
// grid = BB*330 blocks; block g: image b = g/330, output o = g%330.
// Sums partials[b*HH + k][o] over k in [0,512): 2 strided loads/thread
// (L2-resident, 2.75MB working set), LDS tree reduce, one plain store.
__global__ __launch_bounds__(256)
void pan_stage1b(const float* __restrict__ partials,
                 float* __restrict__ chan,   // [BB][SS][CC]
                 float* __restrict__ tex)    // [BB][SS]
{
    const int g = blockIdx.x;
    const int b = g / 330;
    const int o = g % 330;
    const int t = threadIdx.x;

    const float* col = partials + (size_t)b * HH * PB + o;
    float v = col[(size_t)t * PB] + col[(size_t)(t + 256) * PB];

    __shared__ float red[256];
    red[t] = v;
    __syncthreads();
    for (int off = 128; off >= 1; off >>= 1) {
        if (t < off) red[t] += red[t + off];
        __syncthreads();
    }
    if (t == 0) {
        if (o < SS * CC) chan[b * SS * CC + o] = red[0];
        else             tex[b * SS + (o - SS * CC)] = red[0];
    }
}

// ---------------- Stage 2: feats, hierarchy+reg, pairwise loss, tree ----------------
// 1024 threads; 1280-element phases use stride loops.
__global__ __launch_bounds__(1024)
void pan_stage2(const float* __restrict__ chan,
                const float* __restrict__ tex,
                float* __restrict__ out)
{
    __shared__ float feats[BB][SS][CC];   // 1280
    __shared__ float cur1[BB][5][CC];     // 640
    __shared__ float cur2[BB][3][CC];     // 384
    __shared__ float cur3[BB][2][CC];     // 256
    __shared__ float cur4[BB][1][CC];     // 128
    __shared__ float red[1024];
    const int t = threadIdx.x;

    // feats = 0.5 * nodes + 0.5 * texture   (1280 elements, strided)
    for (int i = t; i < BB * SS * CC; i += 1024) {
        int b = i / (SS * CC);
        int s = (i / CC) % SS;
        float node    = chan[i] * (1.0f / (HH * SW));         // /25600
        float texture = tex[b * SS + s] * (1.0f / (CC * CC)); // tsum/1024
        ((float*)feats)[i] = 0.5f * node + 0.5f * texture;
    }
    __syncthreads();

    if (t < BB * 5 * CC) {   // 640
        int b = t / (5 * CC), j = (t / CC) % 5, c = t % CC;
        cur1[b][j][c] = 0.5f * (feats[b][2 * j][c] + feats[b][2 * j + 1][c]);
    }
    __syncthreads();
    if (t < BB * 3 * CC) {   // 384
        int b = t / (3 * CC), j = (t / CC) % 3, c = t % CC;
        cur2[b][j][c] = (j < 2) ? 0.5f * (cur1[b][2 * j][c] + cur1[b][2 * j + 1][c])
                                : cur1[b][4][c];
    }
    __syncthreads();
    if (t < BB * 2 * CC) {   // 256
        int b = t / (2 * CC), j = (t / CC) % 2, c = t % CC;
        cur3[b][j][c] = (j == 0) ? 0.5f * (cur2[b][0][c] + cur2[b][1][c])
                                 : cur2[b][2][c];
    }
    __syncthreads();
    if (t < BB * CC) {       // 128
        int b = t / CC, c = t % CC;
        cur4[b][0][c] = 0.5f * (cur3[b][0][c] + cur3[b][1][c]);
    }
    __syncthreads();

    // reg = sum of per-level means of cur^2
    float rp = 0.0f;
    for (int i = t; i < BB * 5 * CC; i += 1024) { float v = ((float*)cur1)[i]; rp += v * v * (1.0f / (BB * 5 * CC)); }
    for (int i = t; i < BB * 3 * CC; i += 1024) { float v = ((float*)cur2)[i]; rp += v * v * (1.0f / (BB * 3 * CC)); }
    for (int i = t; i < BB * 2 * CC; i += 1024) { float v = ((float*)cur3)[i]; rp += v * v * (1.0f / (BB * 2 * CC)); }
    for (int i = t; i < BB * 1 * CC; i += 1024) { float v = ((float*)cur4)[i]; rp += v * v * (1.0f / (BB * 1 * CC)); }

    // pairwise contrastive term over leaves (400 pairs)
    float lp = 0.0f;
    if (t < BB * SS * SS) {
        int b = t / (SS * SS), i = (t / SS) % SS, j = t % SS;
        float d2 = 0.0f;
#pragma unroll
        for (int c = 0; c < CC; ++c) {
            float df = feats[b][i][c] - feats[b][j][c];
            d2 += df * df;
        }
        float d = sqrtf(d2 + 1e-12f);
        int lev;
        if (i == j) lev = 0;
        else if ((i >> 1) == (j >> 1)) lev = 1;
        else {
            int g2i = (i < 4) ? 0 : ((i < 8) ? 1 : 2);
            int g2j = (j < 4) ? 0 : ((j < 8) ? 1 : 2);
            if (g2i == g2j) lev = 2;
            else if ((i < 8) == (j < 8)) lev = 3;
            else lev = 4;
        }
        float w = 1.0f - 0.25f * (float)lev;
        float m = fmaxf(1.0f - d, 0.0f);
        lp = w * d * d + (1.0f - w) * m * m;
    }

    // reduce pairwise sum
    red[t] = lp;
    __syncthreads();
    for (int off = 512; off >= 1; off >>= 1) {
        if (t < off) red[t] += red[t + off];
        __syncthreads();
    }
    float lsum = red[0];
    __syncthreads();
    // reduce reg partials
    red[t] = rp;
    __syncthreads();
    for (int off = 512; off >= 1; off >>= 1) {
        if (t < off) red[t] += red[t + off];
        __syncthreads();
    }
    if (t == 0) out[BB * 21 * 2] = lsum * (1.0f / (BB * SS * SS)) + 0.01f * red[0];

    // tree: [B, 21, 2] = (parent, level), written as float32 (168 elements)
    if (t < BB * 21 * 2) {
        int g = (t % 42) >> 1;
        int k = t & 1;
        int par, lv;
        if (g < 10)      { par = 10 + (g >> 1);        lv = 0; }
        else if (g < 15) { par = 15 + ((g - 10) >> 1); lv = 1; }
        else if (g < 18) { par = 18 + ((g - 15) >> 1); lv = 2; }
        else if (g < 20) { par = 20;                   lv = 3; }
        else             { par = 20;                   lv = 4; }
        out[t] = (float)(k ? lv : par);
    }
}

extern "C" void kernel_launch(void* const* d_in, const int* in_sizes, int n_in,
                              void* d_out, int out_size, void* d_ws, size_t ws_size,
                              hipStream_t stream) {
    const float* x = (const float*)d_in[0];
    float* out      = (float*)d_out;
    float* ws       = (float*)d_ws;
    float* partials = ws + WS_PARTIALS;    // 2048*336 floats = 2.75 MB
    float* chan     = ws + WS_CHAN;        // 1280 floats
    float* tex      = ws + WS_TEX;         // 40 floats

    // no memset needed: every ws element read is written first within this call
    pan_stage1 <<<NBLK, 256, 0, stream>>>(x, partials);
    pan_stage1b<<<BB * 330, 256, 0, stream>>>(partials, chan, tex);
    pan_stage2 <<<1, 1024, 0, stream>>>(chan, tex, out);
}

// Round 11
// 131.825 us; speedup vs baseline: 1.0979x; 1.0827x over previous
//
#include <hip/hip_runtime.h>

#define BB 4
#define CC 32
#define HH 512
#define WW 500
#define SS 10
#define SW 50
#define P2 (WW / 2)       // 250 float2 columns per row
#define PB 336            // padded partials row: 320 chan + 10 tex + 6 pad
#define NBLK (BB * HH)    // 2048 stage-1 blocks

// ws layout (floats): partials[NBLK][PB] | chan[BB*SS*CC] | tex[BB*SS]
#define WS_PARTIALS 0
#define WS_CHAN (NBLK * PB)
#define WS_TEX  (WS_CHAN + BB * SS * CC)

// ---------------- Stage 1: per-row strip sums -> unique partial slot ----------------
// One block per (b, row); 2048 blocks. __launch_bounds__(256,4): VGPR cap 128 so
// csum[32] stays IN REGISTERS. R8-R10's launch_bounds(256,8) capped VGPRs at 32 and
// spilled csum to scratch: 67 MB writeback + 67 MB re-read per dispatch (WRITE_SIZE
// 70,272 KB constant across three different reduction schemes = the spill signature).
__global__ __launch_bounds__(256, 4)
void pan_stage1(const float* __restrict__ x,
                float* __restrict__ partials)   // [NBLK][PB]
{
    const int tid = threadIdx.x;
    const int blk = blockIdx.x;
    const int b   = blk / HH;
    const int h   = blk % HH;
    const bool active = (tid < P2);
    const int s   = tid / (SW / 2);      // strip (25 float2 per strip)

    __shared__ float lds_c[SS * CC];     // 320 > blockDim: stride loops
    __shared__ float lds_t[SS];
    for (int i = tid; i < SS * CC; i += 256) lds_c[i] = 0.0f;
    if (tid < SS) lds_t[tid] = 0.0f;
    __syncthreads();

    if (active) {
        const float* base = x + (size_t)b * CC * HH * WW + (size_t)h * WW + 2 * tid;
        float csum[CC];
        float gx = 0.0f, gy = 0.0f;
#pragma unroll
        for (int c = 0; c < CC; ++c) {
            const float2 v = *reinterpret_cast<const float2*>(base + (size_t)c * HH * WW);
            csum[c] = v.x + v.y;
            gx += v.x;
            gy += v.y;
        }
#pragma unroll
        for (int c = 0; c < CC; ++c) atomicAdd(&lds_c[s * CC + c], csum[c]);
        atomicAdd(&lds_t[s], gx * gx + gy * gy);
    }
    __syncthreads();

    float* dst = partials + (size_t)blk * PB;
    for (int i = tid; i < SS * CC; i += 256) dst[i] = lds_c[i];          // coalesced
    if (tid < SS) dst[SS * CC + tid] = lds_t[tid];
}

// ---------------- Stage 1b: column-reduce partials -> chan/tex ----------------
// grid = BB*330 blocks; block g: image b = g/330, output o = g%330.
// Sums partials[b*HH + k][o] over k in [0,512): 2 strided loads/thread
// (L2-resident, 2.75MB working set), LDS tree reduce, one plain store.
__global__ __launch_bounds__(256)
void pan_stage1b(const float* __restrict__ partials,
                 float* __restrict__ chan,   // [BB][SS][CC]
                 float* __restrict__ tex)    // [BB][SS]
{
    const int g = blockIdx.x;
    const int b = g / 330;
    const int o = g % 330;
    const int t = threadIdx.x;

    const float* col = partials + (size_t)b * HH * PB + o;
    float v = col[(size_t)t * PB] + col[(size_t)(t + 256) * PB];

    __shared__ float red[256];
    red[t] = v;
    __syncthreads();
    for (int off = 128; off >= 1; off >>= 1) {
        if (t < off) red[t] += red[t + off];
        __syncthreads();
    }
    if (t == 0) {
        if (o < SS * CC) chan[b * SS * CC + o] = red[0];
        else             tex[b * SS + (o - SS * CC)] = red[0];
    }
}

// ---------------- Stage 2: feats, hierarchy+reg, pairwise loss, tree ----------------
// 1024 threads; 1280-element phases use stride loops.
__global__ __launch_bounds__(1024)
void pan_stage2(const float* __restrict__ chan,
                const float* __restrict__ tex,
                float* __restrict__ out)
{
    __shared__ float feats[BB][SS][CC];   // 1280
    __shared__ float cur1[BB][5][CC];     // 640
    __shared__ float cur2[BB][3][CC];     // 384
    __shared__ float cur3[BB][2][CC];     // 256
    __shared__ float cur4[BB][1][CC];     // 128
    __shared__ float red[1024];
    const int t = threadIdx.x;

    // feats = 0.5 * nodes + 0.5 * texture   (1280 elements, strided)
    for (int i = t; i < BB * SS * CC; i += 1024) {
        int b = i / (SS * CC);
        int s = (i / CC) % SS;
        float node    = chan[i] * (1.0f / (HH * SW));         // /25600
        float texture = tex[b * SS + s] * (1.0f / (CC * CC)); // tsum/1024
        ((float*)feats)[i] = 0.5f * node + 0.5f * texture;
    }
    __syncthreads();

    if (t < BB * 5 * CC) {   // 640
        int b = t / (5 * CC), j = (t / CC) % 5, c = t % CC;
        cur1[b][j][c] = 0.5f * (feats[b][2 * j][c] + feats[b][2 * j + 1][c]);
    }
    __syncthreads();
    if (t < BB * 3 * CC) {   // 384
        int b = t / (3 * CC), j = (t / CC) % 3, c = t % CC;
        cur2[b][j][c] = (j < 2) ? 0.5f * (cur1[b][2 * j][c] + cur1[b][2 * j + 1][c])
                                : cur1[b][4][c];
    }
    __syncthreads();
    if (t < BB * 2 * CC) {   // 256
        int b = t / (2 * CC), j = (t / CC) % 2, c = t % CC;
        cur3[b][j][c] = (j == 0) ? 0.5f * (cur2[b][0][c] + cur2[b][1][c])
                                 : cur2[b][2][c];
    }
    __syncthreads();
    if (t < BB * CC) {       // 128
        int b = t / CC, c = t % CC;
        cur4[b][0][c] = 0.5f * (cur3[b][0][c] + cur3[b][1][c]);
    }
    __syncthreads();

    // reg = sum of per-level means of cur^2
    float rp = 0.0f;
    for (int i = t; i < BB * 5 * CC; i += 1024) { float v = ((float*)cur1)[i]; rp += v * v * (1.0f / (BB * 5 * CC)); }
    for (int i = t; i < BB * 3 * CC; i += 1024) { float v = ((float*)cur2)[i]; rp += v * v * (1.0f / (BB * 3 * CC)); }
    for (int i = t; i < BB * 2 * CC; i += 1024) { float v = ((float*)cur3)[i]; rp += v * v * (1.0f / (BB * 2 * CC)); }
    for (int i = t; i < BB * 1 * CC; i += 1024) { float v = ((float*)cur4)[i]; rp += v * v * (1.0f / (BB * 1 * CC)); }

    // pairwise contrastive term over leaves (400 pairs)
    float lp = 0.0f;
    if (t < BB * SS * SS) {
        int b = t / (SS * SS), i = (t / SS) % SS, j = t % SS;
        float d2 = 0.0f;
#pragma unroll
        for (int c = 0; c < CC; ++c) {
            float df = feats[b][i][c] - feats[b][j][c];
            d2 += df * df;
        }
        float d = sqrtf(d2 + 1e-12f);
        int lev;
        if (i == j) lev = 0;
        else if ((i >> 1) == (j >> 1)) lev = 1;
        else {
            int g2i = (i < 4) ? 0 : ((i < 8) ? 1 : 2);
            int g2j = (j < 4) ? 0 : ((j < 8) ? 1 : 2);
            if (g2i == g2j) lev = 2;
            else if ((i < 8) == (j < 8)) lev = 3;
            else lev = 4;
        }
        float w = 1.0f - 0.25f * (float)lev;
        float m = fmaxf(1.0f - d, 0.0f);
        lp = w * d * d + (1.0f - w) * m * m;
    }

    // reduce pairwise sum
    red[t] = lp;
    __syncthreads();
    for (int off = 512; off >= 1; off >>= 1) {
        if (t < off) red[t] += red[t + off];
        __syncthreads();
    }
    float lsum = red[0];
    __syncthreads();
    // reduce reg partials
    red[t] = rp;
    __syncthreads();
    for (int off = 512; off >= 1; off >>= 1) {
        if (t < off) red[t] += red[t + off];
        __syncthreads();
    }
    if (t == 0) out[BB * 21 * 2] = lsum * (1.0f / (BB * SS * SS)) + 0.01f * red[0];

    // tree: [B, 21, 2] = (parent, level), written as float32 (168 elements)
    if (t < BB * 21 * 2) {
        int g = (t % 42) >> 1;
        int k = t & 1;
        int par, lv;
        if (g < 10)      { par = 10 + (g >> 1);        lv = 0; }
        else if (g < 15) { par = 15 + ((g - 10) >> 1); lv = 1; }
        else if (g < 18) { par = 18 + ((g - 15) >> 1); lv = 2; }
        else if (g < 20) { par = 20;                   lv = 3; }
        else             { par = 20;                   lv = 4; }
        out[t] = (float)(k ? lv : par);
    }
}

extern "C" void kernel_launch(void* const* d_in, const int* in_sizes, int n_in,
                              void* d_out, int out_size, void* d_ws, size_t ws_size,
                              hipStream_t stream) {
    const float* x = (const float*)d_in[0];
    float* out      = (float*)d_out;
    float* ws       = (float*)d_ws;
    float* partials = ws + WS_PARTIALS;    // 2048*336 floats = 2.75 MB
    float* chan     = ws + WS_CHAN;        // 1280 floats
    float* tex      = ws + WS_TEX;         // 40 floats

    // no memset needed: every ws element read is written first within this call
    pan_stage1 <<<NBLK, 256, 0, stream>>>(x, partials);
    pan_stage1b<<<BB * 330, 256, 0, stream>>>(partials, chan, tex);
    pan_stage2 <<<1, 1024, 0, stream>>>(chan, tex, out);
}

// Round 12
// 76.038 us; speedup vs baseline: 1.9034x; 1.7337x over previous
//
#include <hip/hip_runtime.h>

#define BB 4
#define CC 32
#define HH 512
#define WW 500
#define SS 10
#define SW 50
#define NQ 125            // 125 float4 columns per row
#define PB 336            // padded partials row: 320 chan + 10 tex + 6 pad
#define NBLK (BB * HH)    // 2048 stage-1 blocks

// ws layout (floats): partials[NBLK][PB] | chan[BB*SS*CC] | tex[BB*SS]
#define WS_PARTIALS 0
#define WS_CHAN (NBLK * PB)
#define WS_TEX  (WS_CHAN + BB * SS * CC)

// ---------------- Stage 1: per-row strip sums -> unique partial slot ----------------
// One block (128 thr = 2 waves) per (b, row); 2048 blocks = 4096 waves = exactly
// 16 waves/CU across 256 CUs. Thread owns one float4 column (4 pixels).
// KEY (R11 lesson): NO per-thread csum[32] -- it pinned 32+ VGPRs and limited the
// load window to ~2, making the kernel latency-bound at ~1 TB/s. Each float4 is
// atomicAdd-ed to LDS immediately; LDS can't alias global so the compiler hoists
// the 16 independent loads into a deep counted-vmcnt pipeline.
__global__ __launch_bounds__(128, 4)
void pan_stage1(const float* __restrict__ x,
                float* __restrict__ partials)   // [NBLK][PB]
{
    const int tid = threadIdx.x;
    const int blk = blockIdx.x;
    const int b   = blk / HH;
    const int h   = blk % HH;
    const bool active = (tid < NQ);
    const int w0  = 4 * tid;
    const int s0  = w0 / SW;
    const int s3  = (w0 + 3) / SW;
    const bool split = (s3 != s0) && active;
    const int m   = split ? (s3 * SW - w0) : 4;   // pixels 0..m-1 -> s0, rest -> s3

    __shared__ float lds_c[SS * CC];
    __shared__ float lds_t[SS];
    for (int i = tid; i < SS * CC; i += 128) lds_c[i] = 0.0f;
    if (tid < SS) lds_t[tid] = 0.0f;
    __syncthreads();

    if (active) {
        const float* base = x + (size_t)b * CC * HH * WW + (size_t)h * WW + w0;
        float g0 = 0.0f, g1 = 0.0f, g2 = 0.0f, g3 = 0.0f;
#pragma unroll
        for (int c = 0; c < CC; ++c) {
            const float4 v = *reinterpret_cast<const float4*>(base + (size_t)c * HH * WW);
            g0 += v.x; g1 += v.y; g2 += v.z; g3 += v.w;
            const float a  = (m > 0 ? v.x : 0.0f) + (m > 1 ? v.y : 0.0f)
                           + (m > 2 ? v.z : 0.0f) + (m > 3 ? v.w : 0.0f);
            atomicAdd(&lds_c[s0 * CC + c], a);
            if (split) {
                const float bb = (m <= 0 ? v.x : 0.0f) + (m <= 1 ? v.y : 0.0f)
                               + (m <= 2 ? v.z : 0.0f) + (m <= 3 ? v.w : 0.0f);
                atomicAdd(&lds_c[s3 * CC + c], bb);
            }
        }
        const float q0 = g0 * g0, q1 = g1 * g1, q2 = g2 * g2, q3 = g3 * g3;
        const float ta = (m > 0 ? q0 : 0.0f) + (m > 1 ? q1 : 0.0f)
                       + (m > 2 ? q2 : 0.0f) + (m > 3 ? q3 : 0.0f);
        atomicAdd(&lds_t[s0], ta);
        if (split) {
            const float tb = (m <= 0 ? q0 : 0.0f) + (m <= 1 ? q1 : 0.0f)
                           + (m <= 2 ? q2 : 0.0f) + (m <= 3 ? q3 : 0.0f);
            atomicAdd(&lds_t[s3], tb);
        }
    }
    __syncthreads();

    float* dst = partials + (size_t)blk * PB;
    for (int i = tid; i < SS * CC; i += 128) dst[i] = lds_c[i];   // coalesced
    if (tid < SS) dst[SS * CC + tid] = lds_t[tid];
}

// ---------------- Stage 1b: column-reduce partials -> chan/tex ----------------
// grid = BB*330 blocks; block g: image b = g/330, output o = g%330.
// Sums partials[b*HH + k][o] over k in [0,512): 2 strided loads/thread
// (L2-resident, 2.75MB working set), LDS tree reduce, one plain store.
__global__ __launch_bounds__(256)
void pan_stage1b(const float* __restrict__ partials,
                 float* __restrict__ chan,   // [BB][SS][CC]
                 float* __restrict__ tex)    // [BB][SS]
{
    const int g = blockIdx.x;
    const int b = g / 330;
    const int o = g % 330;
    const int t = threadIdx.x;

    const float* col = partials + (size_t)b * HH * PB + o;
    float v = col[(size_t)t * PB] + col[(size_t)(t + 256) * PB];

    __shared__ float red[256];
    red[t] = v;
    __syncthreads();
    for (int off = 128; off >= 1; off >>= 1) {
        if (t < off) red[t] += red[t + off];
        __syncthreads();
    }
    if (t == 0) {
        if (o < SS * CC) chan[b * SS * CC + o] = red[0];
        else             tex[b * SS + (o - SS * CC)] = red[0];
    }
}

// ---------------- Stage 2: feats, hierarchy+reg, pairwise loss, tree ----------------
// 1024 threads; 1280-element phases use stride loops.
__global__ __launch_bounds__(1024)
void pan_stage2(const float* __restrict__ chan,
                const float* __restrict__ tex,
                float* __restrict__ out)
{
    __shared__ float feats[BB][SS][CC];   // 1280
    __shared__ float cur1[BB][5][CC];     // 640
    __shared__ float cur2[BB][3][CC];     // 384
    __shared__ float cur3[BB][2][CC];     // 256
    __shared__ float cur4[BB][1][CC];     // 128
    __shared__ float red[1024];
    const int t = threadIdx.x;

    // feats = 0.5 * nodes + 0.5 * texture   (1280 elements, strided)
    for (int i = t; i < BB * SS * CC; i += 1024) {
        int b = i / (SS * CC);
        int s = (i / CC) % SS;
        float node    = chan[i] * (1.0f / (HH * SW));         // /25600
        float texture = tex[b * SS + s] * (1.0f / (CC * CC)); // tsum/1024
        ((float*)feats)[i] = 0.5f * node + 0.5f * texture;
    }
    __syncthreads();

    if (t < BB * 5 * CC) {   // 640
        int b = t / (5 * CC), j = (t / CC) % 5, c = t % CC;
        cur1[b][j][c] = 0.5f * (feats[b][2 * j][c] + feats[b][2 * j + 1][c]);
    }
    __syncthreads();
    if (t < BB * 3 * CC) {   // 384
        int b = t / (3 * CC), j = (t / CC) % 3, c = t % CC;
        cur2[b][j][c] = (j < 2) ? 0.5f * (cur1[b][2 * j][c] + cur1[b][2 * j + 1][c])
                                : cur1[b][4][c];
    }
    __syncthreads();
    if (t < BB * 2 * CC) {   // 256
        int b = t / (2 * CC), j = (t / CC) % 2, c = t % CC;
        cur3[b][j][c] = (j == 0) ? 0.5f * (cur2[b][0][c] + cur2[b][1][c])
                                 : cur2[b][2][c];
    }
    __syncthreads();
    if (t < BB * CC) {       // 128
        int b = t / CC, c = t % CC;
        cur4[b][0][c] = 0.5f * (cur3[b][0][c] + cur3[b][1][c]);
    }
    __syncthreads();

    // reg = sum of per-level means of cur^2
    float rp = 0.0f;
    for (int i = t; i < BB * 5 * CC; i += 1024) { float v = ((float*)cur1)[i]; rp += v * v * (1.0f / (BB * 5 * CC)); }
    for (int i = t; i < BB * 3 * CC; i += 1024) { float v = ((float*)cur2)[i]; rp += v * v * (1.0f / (BB * 3 * CC)); }
    for (int i = t; i < BB * 2 * CC; i += 1024) { float v = ((float*)cur3)[i]; rp += v * v * (1.0f / (BB * 2 * CC)); }
    for (int i = t; i < BB * 1 * CC; i += 1024) { float v = ((float*)cur4)[i]; rp += v * v * (1.0f / (BB * 1 * CC)); }

    // pairwise contrastive term over leaves (400 pairs)
    float lp = 0.0f;
    if (t < BB * SS * SS) {
        int b = t / (SS * SS), i = (t / SS) % SS, j = t % SS;
        float d2 = 0.0f;
#pragma unroll
        for (int c = 0; c < CC; ++c) {
            float df = feats[b][i][c] - feats[b][j][c];
            d2 += df * df;
        }
        float d = sqrtf(d2 + 1e-12f);
        int lev;
        if (i == j) lev = 0;
        else if ((i >> 1) == (j >> 1)) lev = 1;
        else {
            int g2i = (i < 4) ? 0 : ((i < 8) ? 1 : 2);
            int g2j = (j < 4) ? 0 : ((j < 8) ? 1 : 2);
            if (g2i == g2j) lev = 2;
            else if ((i < 8) == (j < 8)) lev = 3;
            else lev = 4;
        }
        float w = 1.0f - 0.25f * (float)lev;
        float m = fmaxf(1.0f - d, 0.0f);
        lp = w * d * d + (1.0f - w) * m * m;
    }

    // reduce pairwise sum
    red[t] = lp;
    __syncthreads();
    for (int off = 512; off >= 1; off >>= 1) {
        if (t < off) red[t] += red[t + off];
        __syncthreads();
    }
    float lsum = red[0];
    __syncthreads();
    // reduce reg partials
    red[t] = rp;
    __syncthreads();
    for (int off = 512; off >= 1; off >>= 1) {
        if (t < off) red[t] += red[t + off];
        __syncthreads();
    }
    if (t == 0) out[BB * 21 * 2] = lsum * (1.0f / (BB * SS * SS)) + 0.01f * red[0];

    // tree: [B, 21, 2] = (parent, level), written as float32 (168 elements)
    if (t < BB * 21 * 2) {
        int g = (t % 42) >> 1;
        int k = t & 1;
        int par, lv;
        if (g < 10)      { par = 10 + (g >> 1);        lv = 0; }
        else if (g < 15) { par = 15 + ((g - 10) >> 1); lv = 1; }
        else if (g < 18) { par = 18 + ((g - 15) >> 1); lv = 2; }
        else if (g < 20) { par = 20;                   lv = 3; }
        else             { par = 20;                   lv = 4; }
        out[t] = (float)(k ? lv : par);
    }
}

extern "C" void kernel_launch(void* const* d_in, const int* in_sizes, int n_in,
                              void* d_out, int out_size, void* d_ws, size_t ws_size,
                              hipStream_t stream) {
    const float* x = (const float*)d_in[0];
    float* out      = (float*)d_out;
    float* ws       = (float*)d_ws;
    float* partials = ws + WS_PARTIALS;    // 2048*336 floats = 2.75 MB
    float* chan     = ws + WS_CHAN;        // 1280 floats
    float* tex      = ws + WS_TEX;         // 40 floats

    // no memset needed: every ws element read is written first within this call
    pan_stage1 <<<NBLK, 128, 0, stream>>>(x, partials);
    pan_stage1b<<<BB * 330, 256, 0, stream>>>(partials, chan, tex);
    pan_stage2 <<<1, 1024, 0, stream>>>(chan, tex, out);
}

// Round 13
// 60.585 us; speedup vs baseline: 2.3889x; 1.2551x over previous
//
#include <hip/hip_runtime.h>

#define BB 4
#define CC 32
#define HH 512
#define WW 500
#define SS 10
#define SW 50
#define NQ 125            // 125 float4 columns per row
#define PB 336            // padded partials row: 320 chan + 10 tex + 6 pad
#define NR2 (HH / 2)      // 256 row-pairs per image
#define NBLK2 (BB * NR2)  // 1024 stage-1 blocks

// ws layout (floats): partials[NBLK2][PB] | chan[BB*SS*CC] | tex[BB*SS]
#define WS_CHAN (NBLK2 * PB)
#define WS_TEX  (WS_CHAN + BB * SS * CC)

// ---------------- Stage 1: two-row strip sums -> unique partial slot ----------------
// Block (128 thr) owns rows (2j, 2j+1) of image b; thread owns one float4 column in
// BOTH rows. vs R12: atomics halved (two rows merge in-register before one LDS
// atomicAdd) and 64 independent loads/thread (2/channel) -> deep vmcnt window.
// Strips: w0=4*tid spans <=2 strips; split threads always have m=2 (odd 50-multiples
// land mid-float4 only at offset 2).
__global__ __launch_bounds__(128, 4)
void pan_stage1(const float* __restrict__ x,
                float* __restrict__ partials)   // [NBLK2][PB]
{
    const int tid = threadIdx.x;
    const int blk = blockIdx.x;
    const int b   = blk >> 8;            // blk / NR2
    const int j   = blk & (NR2 - 1);
    const bool active = (tid < NQ);
    const int w0  = 4 * tid;
    const int s0  = w0 / SW;
    const int s3  = (w0 + 3) / SW;
    const bool split = (s3 != s0) && active;   // m==2 when split

    __shared__ float lds_c[SS * CC];
    __shared__ float lds_t[SS];
    for (int i = tid; i < SS * CC; i += 128) lds_c[i] = 0.0f;
    if (tid < SS) lds_t[tid] = 0.0f;
    __syncthreads();

    if (active) {
        const float* base = x + (size_t)b * CC * HH * WW + (size_t)(2 * j) * WW + w0;
        float g00 = 0.f, g01 = 0.f, g02 = 0.f, g03 = 0.f;   // row0 per-pixel gray sums
        float g10 = 0.f, g11 = 0.f, g12 = 0.f, g13 = 0.f;   // row1
#pragma unroll
        for (int c = 0; c < CC; ++c) {
            const float* pc = base + (size_t)c * HH * WW;
            const float4 v0 = *reinterpret_cast<const float4*>(pc);
            const float4 v1 = *reinterpret_cast<const float4*>(pc + WW);
            g00 += v0.x; g01 += v0.y; g02 += v0.z; g03 += v0.w;
            g10 += v1.x; g11 += v1.y; g12 += v1.z; g13 += v1.w;
            const float hi = v0.z + v0.w + v1.z + v1.w;
            const float a  = v0.x + v0.y + v1.x + v1.y + (split ? 0.0f : hi);
            atomicAdd(&lds_c[s0 * CC + c], a);
            if (split) atomicAdd(&lds_c[s3 * CC + c], hi);
        }
        const float qlo = g00 * g00 + g01 * g01 + g10 * g10 + g11 * g11;
        const float qhi = g02 * g02 + g03 * g03 + g12 * g12 + g13 * g13;
        if (split) {
            atomicAdd(&lds_t[s0], qlo);
            atomicAdd(&lds_t[s3], qhi);
        } else {
            atomicAdd(&lds_t[s0], qlo + qhi);
        }
    }
    __syncthreads();

    float* dst = partials + (size_t)blk * PB;
    for (int i = tid; i < SS * CC; i += 128) dst[i] = lds_c[i];   // coalesced
    if (tid < SS) dst[SS * CC + tid] = lds_t[tid];
}

// ---------------- Stage 1b: column-reduce partials -> chan/tex ----------------
// One wave per output: grid = BB*330; thread t sums rows t, t+64, t+128, t+192
// of the image's 256 partial rows (L2-resident), 6-step shuffle reduce, lane-0 store.
__global__ __launch_bounds__(64)
void pan_stage1b(const float* __restrict__ partials,
                 float* __restrict__ chan,   // [BB][SS][CC]
                 float* __restrict__ tex)    // [BB][SS]
{
    const int g = blockIdx.x;
    const int b = g / 330;
    const int o = g % 330;
    const int t = threadIdx.x;

    const float* col = partials + (size_t)b * NR2 * PB + o;
    float v = 0.0f;
#pragma unroll
    for (int i = 0; i < 4; ++i) v += col[(size_t)(t + 64 * i) * PB];
#pragma unroll
    for (int off = 32; off >= 1; off >>= 1) v += __shfl_xor(v, off, 64);
    if (t == 0) {
        if (o < SS * CC) chan[b * SS * CC + o] = v;
        else             tex[b * SS + (o - SS * CC)] = v;
    }
}

// ---------------- Stage 2: feats, hierarchy+reg, pairwise loss, tree ----------------
// 1024 threads; 1280-element phases use stride loops.
__global__ __launch_bounds__(1024)
void pan_stage2(const float* __restrict__ chan,
                const float* __restrict__ tex,
                float* __restrict__ out)
{
    __shared__ float feats[BB][SS][CC];   // 1280
    __shared__ float cur1[BB][5][CC];     // 640
    __shared__ float cur2[BB][3][CC];     // 384
    __shared__ float cur3[BB][2][CC];     // 256
    __shared__ float cur4[BB][1][CC];     // 128
    __shared__ float red[1024];
    const int t = threadIdx.x;

    // feats = 0.5 * nodes + 0.5 * texture   (1280 elements, strided)
    for (int i = t; i < BB * SS * CC; i += 1024) {
        int b = i / (SS * CC);
        int s = (i / CC) % SS;
        float node    = chan[i] * (1.0f / (HH * SW));         // /25600
        float texture = tex[b * SS + s] * (1.0f / (CC * CC)); // tsum/1024
        ((float*)feats)[i] = 0.5f * node + 0.5f * texture;
    }
    __syncthreads();

    if (t < BB * 5 * CC) {   // 640
        int b = t / (5 * CC), j = (t / CC) % 5, c = t % CC;
        cur1[b][j][c] = 0.5f * (feats[b][2 * j][c] + feats[b][2 * j + 1][c]);
    }
    __syncthreads();
    if (t < BB * 3 * CC) {   // 384
        int b = t / (3 * CC), j = (t / CC) % 3, c = t % CC;
        cur2[b][j][c] = (j < 2) ? 0.5f * (cur1[b][2 * j][c] + cur1[b][2 * j + 1][c])
                                : cur1[b][4][c];
    }
    __syncthreads();
    if (t < BB * 2 * CC) {   // 256
        int b = t / (2 * CC), j = (t / CC) % 2, c = t % CC;
        cur3[b][j][c] = (j == 0) ? 0.5f * (cur2[b][0][c] + cur2[b][1][c])
                                 : cur2[b][2][c];
    }
    __syncthreads();
    if (t < BB * CC) {       // 128
        int b = t / CC, c = t % CC;
        cur4[b][0][c] = 0.5f * (cur3[b][0][c] + cur3[b][1][c]);
    }
    __syncthreads();

    // reg = sum of per-level means of cur^2
    float rp = 0.0f;
    for (int i = t; i < BB * 5 * CC; i += 1024) { float v = ((float*)cur1)[i]; rp += v * v * (1.0f / (BB * 5 * CC)); }
    for (int i = t; i < BB * 3 * CC; i += 1024) { float v = ((float*)cur2)[i]; rp += v * v * (1.0f / (BB * 3 * CC)); }
    for (int i = t; i < BB * 2 * CC; i += 1024) { float v = ((float*)cur3)[i]; rp += v * v * (1.0f / (BB * 2 * CC)); }
    for (int i = t; i < BB * 1 * CC; i += 1024) { float v = ((float*)cur4)[i]; rp += v * v * (1.0f / (BB * 1 * CC)); }

    // pairwise contrastive term over leaves (400 pairs)
    float lp = 0.0f;
    if (t < BB * SS * SS) {
        int b = t / (SS * SS), i = (t / SS) % SS, j = t % SS;
        float d2 = 0.0f;
#pragma unroll
        for (int c = 0; c < CC; ++c) {
            float df = feats[b][i][c] - feats[b][j][c];
            d2 += df * df;
        }
        float d = sqrtf(d2 + 1e-12f);
        int lev;
        if (i == j) lev = 0;
        else if ((i >> 1) == (j >> 1)) lev = 1;
        else {
            int g2i = (i < 4) ? 0 : ((i < 8) ? 1 : 2);
            int g2j = (j < 4) ? 0 : ((j < 8) ? 1 : 2);
            if (g2i == g2j) lev = 2;
            else if ((i < 8) == (j < 8)) lev = 3;
            else lev = 4;
        }
        float w = 1.0f - 0.25f * (float)lev;
        float m = fmaxf(1.0f - d, 0.0f);
        lp = w * d * d + (1.0f - w) * m * m;
    }

    // reduce pairwise sum
    red[t] = lp;
    __syncthreads();
    for (int off = 512; off >= 1; off >>= 1) {
        if (t < off) red[t] += red[t + off];
        __syncthreads();
    }
    float lsum = red[0];
    __syncthreads();
    // reduce reg partials
    red[t] = rp;
    __syncthreads();
    for (int off = 512; off >= 1; off >>= 1) {
        if (t < off) red[t] += red[t + off];
        __syncthreads();
    }
    if (t == 0) out[BB * 21 * 2] = lsum * (1.0f / (BB * SS * SS)) + 0.01f * red[0];

    // tree: [B, 21, 2] = (parent, level), written as float32 (168 elements)
    if (t < BB * 21 * 2) {
        int g = (t % 42) >> 1;
        int k = t & 1;
        int par, lv;
        if (g < 10)      { par = 10 + (g >> 1);        lv = 0; }
        else if (g < 15) { par = 15 + ((g - 10) >> 1); lv = 1; }
        else if (g < 18) { par = 18 + ((g - 15) >> 1); lv = 2; }
        else if (g < 20) { par = 20;                   lv = 3; }
        else             { par = 20;                   lv = 4; }
        out[t] = (float)(k ? lv : par);
    }
}

extern "C" void kernel_launch(void* const* d_in, const int* in_sizes, int n_in,
                              void* d_out, int out_size, void* d_ws, size_t ws_size,
                              hipStream_t stream) {
    const float* x = (const float*)d_in[0];
    float* out      = (float*)d_out;
    float* ws       = (float*)d_ws;
    float* partials = ws;                  // 1024*336 floats = 1.38 MB
    float* chan     = ws + WS_CHAN;        // 1280 floats
    float* tex      = ws + WS_TEX;         // 40 floats

    // no memset needed: every ws element read is written first within this call
    pan_stage1 <<<NBLK2, 128, 0, stream>>>(x, partials);
    pan_stage1b<<<BB * 330, 64, 0, stream>>>(partials, chan, tex);
    pan_stage2 <<<1, 1024, 0, stream>>>(chan, tex, out);
}

// Round 14
// 44.361 us; speedup vs baseline: 3.2625x; 1.3657x over previous
//
#include <hip/hip_runtime.h>

#define BB 4
#define CC 32
#define HH 512
#define WW 500
#define SS 10
#define SW 50
#define NQ 125            // 125 float4 columns per row
#define PB 336            // padded partials row: 320 chan + 10 tex + 6 pad
#define NR2 (HH / 2)      // 256 row-pairs per image
#define NBLK2 (BB * NR2)  // 1024 stage-1 blocks

// ws layout (floats): partials[NBLK2][PB] | chan[BB*SS*CC] | tex[BB*SS]
#define WS_CHAN (NBLK2 * PB)
#define WS_TEX  (WS_CHAN + BB * SS * CC)

// ---------------- Stage 1: two-row strip sums -> unique partial slot ----------------
// Block (128 thr) owns rows (2j, 2j+1); thread owns one float4 column in BOTH rows.
// R13 lesson: full unroll (64 hoistable loads) + VGPR cap 64 made the compiler spill
// ~36 float4/thread through scratch (WRITE_SIZE 74 MB). Fix: unroll 8 (16-load
// window = 64 VGPRs, fits) + no min-occupancy arg (cap 256; grid already limits
// occupancy to 4 blocks/CU, the cap only stole register headroom).
__global__ __launch_bounds__(128)
void pan_stage1(const float* __restrict__ x,
                float* __restrict__ partials)   // [NBLK2][PB]
{
    const int tid = threadIdx.x;
    const int blk = blockIdx.x;
    const int b   = blk >> 8;            // blk / NR2
    const int j   = blk & (NR2 - 1);
    const bool active = (tid < NQ);
    const int w0  = 4 * tid;
    const int s0  = w0 / SW;
    const int s3  = (w0 + 3) / SW;
    const bool split = (s3 != s0) && active;   // m==2 when split

    __shared__ float lds_c[SS * CC];
    __shared__ float lds_t[SS];
    for (int i = tid; i < SS * CC; i += 128) lds_c[i] = 0.0f;
    if (tid < SS) lds_t[tid] = 0.0f;
    __syncthreads();

    if (active) {
        const float* base = x + (size_t)b * CC * HH * WW + (size_t)(2 * j) * WW + w0;
        float g00 = 0.f, g01 = 0.f, g02 = 0.f, g03 = 0.f;   // row0 per-pixel gray sums
        float g10 = 0.f, g11 = 0.f, g12 = 0.f, g13 = 0.f;   // row1
#pragma unroll 8
        for (int c = 0; c < CC; ++c) {
            const float* pc = base + (size_t)c * HH * WW;
            const float4 v0 = *reinterpret_cast<const float4*>(pc);
            const float4 v1 = *reinterpret_cast<const float4*>(pc + WW);
            g00 += v0.x; g01 += v0.y; g02 += v0.z; g03 += v0.w;
            g10 += v1.x; g11 += v1.y; g12 += v1.z; g13 += v1.w;
            const float hi = v0.z + v0.w + v1.z + v1.w;
            const float a  = v0.x + v0.y + v1.x + v1.y + (split ? 0.0f : hi);
            atomicAdd(&lds_c[s0 * CC + c], a);
            if (split) atomicAdd(&lds_c[s3 * CC + c], hi);
        }
        const float qlo = g00 * g00 + g01 * g01 + g10 * g10 + g11 * g11;
        const float qhi = g02 * g02 + g03 * g03 + g12 * g12 + g13 * g13;
        if (split) {
            atomicAdd(&lds_t[s0], qlo);
            atomicAdd(&lds_t[s3], qhi);
        } else {
            atomicAdd(&lds_t[s0], qlo + qhi);
        }
    }
    __syncthreads();

    float* dst = partials + (size_t)blk * PB;
    for (int i = tid; i < SS * CC; i += 128) dst[i] = lds_c[i];   // coalesced
    if (tid < SS) dst[SS * CC + tid] = lds_t[tid];
}

// ---------------- Stage 1b: column-reduce partials -> chan/tex ----------------
// One wave per output: grid = BB*330; thread t sums rows t, t+64, t+128, t+192
// of the image's 256 partial rows (L2-resident), 6-step shuffle reduce, lane-0 store.
__global__ __launch_bounds__(64)
void pan_stage1b(const float* __restrict__ partials,
                 float* __restrict__ chan,   // [BB][SS][CC]
                 float* __restrict__ tex)    // [BB][SS]
{
    const int g = blockIdx.x;
    const int b = g / 330;
    const int o = g % 330;
    const int t = threadIdx.x;

    const float* col = partials + (size_t)b * NR2 * PB + o;
    float v = 0.0f;
#pragma unroll
    for (int i = 0; i < 4; ++i) v += col[(size_t)(t + 64 * i) * PB];
#pragma unroll
    for (int off = 32; off >= 1; off >>= 1) v += __shfl_xor(v, off, 64);
    if (t == 0) {
        if (o < SS * CC) chan[b * SS * CC + o] = v;
        else             tex[b * SS + (o - SS * CC)] = v;
    }
}

// ---------------- Stage 2: feats, hierarchy+reg, pairwise loss, tree ----------------
// 1024 threads; 1280-element phases use stride loops.
__global__ __launch_bounds__(1024)
void pan_stage2(const float* __restrict__ chan,
                const float* __restrict__ tex,
                float* __restrict__ out)
{
    __shared__ float feats[BB][SS][CC];   // 1280
    __shared__ float cur1[BB][5][CC];     // 640
    __shared__ float cur2[BB][3][CC];     // 384
    __shared__ float cur3[BB][2][CC];     // 256
    __shared__ float cur4[BB][1][CC];     // 128
    __shared__ float red[1024];
    const int t = threadIdx.x;

    // feats = 0.5 * nodes + 0.5 * texture   (1280 elements, strided)
    for (int i = t; i < BB * SS * CC; i += 1024) {
        int b = i / (SS * CC);
        int s = (i / CC) % SS;
        float node    = chan[i] * (1.0f / (HH * SW));         // /25600
        float texture = tex[b * SS + s] * (1.0f / (CC * CC)); // tsum/1024
        ((float*)feats)[i] = 0.5f * node + 0.5f * texture;
    }
    __syncthreads();

    if (t < BB * 5 * CC) {   // 640
        int b = t / (5 * CC), j = (t / CC) % 5, c = t % CC;
        cur1[b][j][c] = 0.5f * (feats[b][2 * j][c] + feats[b][2 * j + 1][c]);
    }
    __syncthreads();
    if (t < BB * 3 * CC) {   // 384
        int b = t / (3 * CC), j = (t / CC) % 3, c = t % CC;
        cur2[b][j][c] = (j < 2) ? 0.5f * (cur1[b][2 * j][c] + cur1[b][2 * j + 1][c])
                                : cur1[b][4][c];
    }
    __syncthreads();
    if (t < BB * 2 * CC) {   // 256
        int b = t / (2 * CC), j = (t / CC) % 2, c = t % CC;
        cur3[b][j][c] = (j == 0) ? 0.5f * (cur2[b][0][c] + cur2[b][1][c])
                                 : cur2[b][2][c];
    }
    __syncthreads();
    if (t < BB * CC) {       // 128
        int b = t / CC, c = t % CC;
        cur4[b][0][c] = 0.5f * (cur3[b][0][c] + cur3[b][1][c]);
    }
    __syncthreads();

    // reg = sum of per-level means of cur^2
    float rp = 0.0f;
    for (int i = t; i < BB * 5 * CC; i += 1024) { float v = ((float*)cur1)[i]; rp += v * v * (1.0f / (BB * 5 * CC)); }
    for (int i = t; i < BB * 3 * CC; i += 1024) { float v = ((float*)cur2)[i]; rp += v * v * (1.0f / (BB * 3 * CC)); }
    for (int i = t; i < BB * 2 * CC; i += 1024) { float v = ((float*)cur3)[i]; rp += v * v * (1.0f / (BB * 2 * CC)); }
    for (int i = t; i < BB * 1 * CC; i += 1024) { float v = ((float*)cur4)[i]; rp += v * v * (1.0f / (BB * 1 * CC)); }

    // pairwise contrastive term over leaves (400 pairs)
    float lp = 0.0f;
    if (t < BB * SS * SS) {
        int b = t / (SS * SS), i = (t / SS) % SS, j = t % SS;
        float d2 = 0.0f;
#pragma unroll
        for (int c = 0; c < CC; ++c) {
            float df = feats[b][i][c] - feats[b][j][c];
            d2 += df * df;
        }
        float d = sqrtf(d2 + 1e-12f);
        int lev;
        if (i == j) lev = 0;
        else if ((i >> 1) == (j >> 1)) lev = 1;
        else {
            int g2i = (i < 4) ? 0 : ((i < 8) ? 1 : 2);
            int g2j = (j < 4) ? 0 : ((j < 8) ? 1 : 2);
            if (g2i == g2j) lev = 2;
            else if ((i < 8) == (j < 8)) lev = 3;
            else lev = 4;
        }
        float w = 1.0f - 0.25f * (float)lev;
        float m = fmaxf(1.0f - d, 0.0f);
        lp = w * d * d + (1.0f - w) * m * m;
    }

    // reduce pairwise sum
    red[t] = lp;
    __syncthreads();
    for (int off = 512; off >= 1; off >>= 1) {
        if (t < off) red[t] += red[t + off];
        __syncthreads();
    }
    float lsum = red[0];
    __syncthreads();
    // reduce reg partials
    red[t] = rp;
    __syncthreads();
    for (int off = 512; off >= 1; off >>= 1) {
        if (t < off) red[t] += red[t + off];
        __syncthreads();
    }
    if (t == 0) out[BB * 21 * 2] = lsum * (1.0f / (BB * SS * SS)) + 0.01f * red[0];

    // tree: [B, 21, 2] = (parent, level), written as float32 (168 elements)
    if (t < BB * 21 * 2) {
        int g = (t % 42) >> 1;
        int k = t & 1;
        int par, lv;
        if (g < 10)      { par = 10 + (g >> 1);        lv = 0; }
        else if (g < 15) { par = 15 + ((g - 10) >> 1); lv = 1; }
        else if (g < 18) { par = 18 + ((g - 15) >> 1); lv = 2; }
        else if (g < 20) { par = 20;                   lv = 3; }
        else             { par = 20;                   lv = 4; }
        out[t] = (float)(k ? lv : par);
    }
}

extern "C" void kernel_launch(void* const* d_in, const int* in_sizes, int n_in,
                              void* d_out, int out_size, void* d_ws, size_t ws_size,
                              hipStream_t stream) {
    const float* x = (const float*)d_in[0];
    float* out      = (float*)d_out;
    float* ws       = (float*)d_ws;
    float* partials = ws;                  // 1024*336 floats = 1.38 MB
    float* chan     = ws + WS_CHAN;        // 1280 floats
    float* tex      = ws + WS_TEX;         // 40 floats

    // no memset needed: every ws element read is written first within this call
    pan_stage1 <<<NBLK2, 128, 0, stream>>>(x, partials);
    pan_stage1b<<<BB * 330, 64, 0, stream>>>(partials, chan, tex);
    pan_stage2 <<<1, 1024, 0, stream>>>(chan, tex, out);
}